// Round 4
// baseline (335.889 us; speedup 1.0000x reference)
//
#include <hip/hip_runtime.h>

#define BB   16384
#define GENC 216
#define OBS  512
#define NH   1024
#define NC   64
#define NFAC 8
#define NIN  1240
#define KP1  1280   // layer-1 K padded to multiple of 64
#define MTILES 136  // worst-case sum of ceil(cnt_f/128): 128 + 8 partials

typedef __attribute__((ext_vector_type(4))) float f32x4;
typedef __attribute__((ext_vector_type(8))) short short8;
typedef __attribute__((ext_vector_type(4))) short short4v;

__device__ __forceinline__ unsigned short f2bf(float f) {
  union { float f; unsigned u; } x; x.f = f;
  unsigned r = x.u + 0x7fffu + ((x.u >> 16) & 1u);
  return (unsigned short)(r >> 16);
}

__device__ __forceinline__ void gl_lds16(const unsigned short* g, unsigned short* l) {
  __builtin_amdgcn_global_load_lds(
      (const __attribute__((address_space(1))) void*)g,
      (__attribute__((address_space(3))) void*)l, 16, 0, 0);
}

// ---------- bucket: per-row last-active factor, LDS-aggregated atomics ----------
__global__ void bucket_kernel(const float* __restrict__ graph,
                              int* __restrict__ cnt, int* __restrict__ rowlist) {
  __shared__ int lcnt[NFAC];
  __shared__ int lbase[NFAC];
  int tid = threadIdx.x;
  if (tid < NFAC) lcnt[tid] = 0;
  __syncthreads();
  int b = blockIdx.x * 256 + tid;
  const float* g = graph + (size_t)b * GENC;
  float4 g0 = *(const float4*)g;
  float4 g1 = *(const float4*)(g + 4);
  int f = -1;
  if (g0.x == 1.f) f = 0;
  if (g0.y == 1.f) f = 1;
  if (g0.z == 1.f) f = 2;
  if (g0.w == 1.f) f = 3;
  if (g1.x == 1.f) f = 4;
  if (g1.y == 1.f) f = 5;
  if (g1.z == 1.f) f = 6;
  if (g1.w == 1.f) f = 7;
  int li = 0;
  if (f >= 0) li = atomicAdd(&lcnt[f], 1);
  __syncthreads();
  if (tid < NFAC) lbase[tid] = lcnt[tid] ? atomicAdd(&cnt[tid], lcnt[tid]) : 0;
  __syncthreads();
  if (f >= 0) rowlist[f * BB + lbase[f] + li] = b;
}

// -------- gather active rows (global position), concat + f32->bf16, pad to 1280 --------
__global__ void gather_x(const float* __restrict__ graph,
                         const float* __restrict__ state,
                         const float* __restrict__ nexts,
                         const int* __restrict__ cnt,
                         const int* __restrict__ rowlist,
                         unsigned short* __restrict__ xg) {
  int w = threadIdx.x >> 6, lane = threadIdx.x & 63;
  int pos = blockIdx.x * 4 + w;
  int f = -1, loc = 0, acc = 0;
#pragma unroll
  for (int i = 0; i < NFAC; ++i) {
    int c = cnt[i];
    if (f < 0 && pos < acc + c) { f = i; loc = pos - acc; }
    acc += c;
  }
  if (f < 0) return;  // pos >= total active rows
  int b = rowlist[f * BB + loc];
  unsigned short* dst = xg + (size_t)pos * KP1;
#pragma unroll
  for (int it = 0; it < 5; ++it) {
    int c = it * 64 + lane;  // float4 chunk index, 320 total
    float4 v;
    if (c < 54)       v = *(const float4*)(graph + (size_t)b * GENC + c * 4);
    else if (c < 182) v = *(const float4*)(state + (size_t)b * OBS + (c - 54) * 4);
    else if (c < 310) v = *(const float4*)(nexts + (size_t)b * OBS + (c - 182) * 4);
    else              v = make_float4(0.f, 0.f, 0.f, 0.f);
    short4v s;
    s[0] = (short)f2bf(v.x); s[1] = (short)f2bf(v.y);
    s[2] = (short)f2bf(v.z); s[3] = (short)f2bf(v.w);
    *(short4v*)(dst + c * 4) = s;
  }
}

// ---- merged transpose+convert: f32 [F][K][N] -> bf16 [F][N][KPad] for W1,W2,W3 ----
__global__ void transpose_all(const float* __restrict__ W1,
                              const float* __restrict__ W2,
                              const float* __restrict__ W3,
                              unsigned short* __restrict__ w1t,
                              unsigned short* __restrict__ w2t,
                              unsigned short* __restrict__ w3t) {
  __shared__ unsigned short tile[64][65];
  int z = blockIdx.z;
  const float* src; unsigned short* dst; int K, N, KPad;
  if (z < 8)        { src = W1 + (size_t)z * NIN * NH;       dst = w1t + (size_t)z * NH * KP1; K = NIN; N = NH; KPad = KP1; }
  else if (z < 16)  { src = W2 + (size_t)(z - 8) * NH * NH;  dst = w2t + (size_t)(z - 8) * NH * NH; K = NH; N = NH; KPad = NH; }
  else              { src = W3 + (size_t)(z - 16) * NH * NC; dst = w3t + (size_t)(z - 16) * NC * NH; K = NH; N = NC; KPad = NH; }
  int k0 = blockIdx.y * 64, n0 = blockIdx.x * 64;
  if (k0 >= KPad || n0 >= N) return;
  int tr = threadIdx.x >> 6, tc = threadIdx.x & 63;  // tc = n offset
#pragma unroll
  for (int i = 0; i < 16; ++i) {
    int r = i * 4 + tr;  // k offset
    int k = k0 + r;
    float v = (k < K) ? src[(size_t)k * N + n0 + tc] : 0.0f;
    tile[r][tc] = f2bf(v);
  }
  __syncthreads();
  int kp = threadIdx.x & 31, nb = threadIdx.x >> 5;  // 32 k-pairs x 8 n-slots
#pragma unroll
  for (int i = 0; i < 8; ++i) {
    int n = i * 8 + nb;
    union { short2 s2; unsigned u; } v;
    v.s2.x = (short)tile[kp * 2][n];
    v.s2.y = (short)tile[kp * 2 + 1][n];
    *(unsigned*)(dst + (size_t)(n0 + n) * KPad + k0 + kp * 2) = v.u;
  }
}

// ---------------- grouped GEMM, m97 structure, tile-ID mapped ----------------
template <int LAYER>
__launch_bounds__(256, 4)
__global__ void mlp_gemm(const unsigned short* __restrict__ Abase,
                         const unsigned short* __restrict__ Wt,
                         const float* __restrict__ bias,
                         unsigned short* __restrict__ Hout,
                         float* __restrict__ Out,
                         const int* __restrict__ cnt,
                         const int* __restrict__ rowlist) {
  constexpr int N  = (LAYER == 3) ? NC : NH;
  constexpr int K  = (LAYER == 1) ? KP1 : NH;
  constexpr int BM = 128;
  constexpr int BN = (LAYER == 3) ? 64 : 128;
  constexpr int NKT = K / 64;
  constexpr int MF = (LAYER == 3) ? 2 : 4;
  constexpr int BI = (LAYER == 3) ? 2 : 4;  // B stage issues/wave

  // map tile id -> (factor, m0, group offset)
  const int ty = blockIdx.y;
  int f = -1, m0 = 0, goff = 0, cntf = 0;
  {
    int acc = 0, off = 0;
#pragma unroll
    for (int i = 0; i < NFAC; ++i) {
      int c = cnt[i];
      int t = (c + BM - 1) >> 7;
      if (f < 0 && ty < acc + t) { f = i; m0 = (ty - acc) * BM; goff = off; cntf = c; }
      acc += t; off += c;
    }
  }
  if (f < 0) return;
  const int n0 = blockIdx.x * BN;

  __shared__ unsigned short As[BM * 64];
  __shared__ unsigned short Bs[BN * 64];

  const int tid = threadIdx.x;
  const int wid = tid >> 6, lane = tid & 63;
  const int wm = (LAYER == 3) ? wid : (wid >> 1);
  const int wn = (LAYER == 3) ? 0 : (wid & 1);

  // per-lane pre-swizzled staging sources (linear LDS dest, swizzled source)
  const int rl = lane >> 3;         // row within 8-row stage group
  const int chs = (lane & 7) ^ rl;  // swizzled 16B chunk
  const unsigned short* pA[4];
  const unsigned short* pB[BI];
  {
    const unsigned short* Aorg = Abase + (size_t)(goff + m0) * K;
    const unsigned short* Borg = Wt + (size_t)f * N * K + (size_t)n0 * K;
#pragma unroll
    for (int i = 0; i < 4; ++i)
      pA[i] = Aorg + (size_t)(wid * 32 + i * 8 + rl) * K + chs * 8;
#pragma unroll
    for (int i = 0; i < BI; ++i)
      pB[i] = Borg + (size_t)(wid * (8 * BI) + i * 8 + rl) * K + chs * 8;
  }

  f32x4 acc[MF][4];
#pragma unroll
  for (int a = 0; a < MF; ++a)
#pragma unroll
    for (int b = 0; b < 4; ++b) acc[a][b] = (f32x4){0.f, 0.f, 0.f, 0.f};

  for (int kt = 0; kt < NKT; ++kt) {
#pragma unroll
    for (int i = 0; i < 4; ++i) {
      gl_lds16(pA[i], &As[(wid * 32 + i * 8) * 64]);
      pA[i] += 64;
    }
#pragma unroll
    for (int i = 0; i < BI; ++i) {
      gl_lds16(pB[i], &Bs[(wid * (8 * BI) + i * 8) * 64]);
      pB[i] += 64;
    }
    __syncthreads();
#pragma unroll
    for (int ks = 0; ks < 2; ++ks) {
      const int kc8 = ks * 4 + (lane >> 4);  // logical 8-elem chunk 0..7
      short8 av[MF], bv[4];
#pragma unroll
      for (int mf = 0; mf < MF; ++mf) {
        int row = wm * (MF * 16) + mf * 16 + (lane & 15);
        av[mf] = *(const short8*)(As + row * 64 + ((kc8 ^ (row & 7)) << 3));
      }
#pragma unroll
      for (int nf = 0; nf < 4; ++nf) {
        int col = wn * 64 + nf * 16 + (lane & 15);
        bv[nf] = *(const short8*)(Bs + col * 64 + ((kc8 ^ (col & 7)) << 3));
      }
#pragma unroll
      for (int mf = 0; mf < MF; ++mf)
#pragma unroll
        for (int nf = 0; nf < 4; ++nf)
          acc[mf][nf] = __builtin_amdgcn_mfma_f32_16x16x32_bf16(
              av[mf], bv[nf], acc[mf][nf], 0, 0, 0);
    }
    __syncthreads();
  }

  // ---- epilogue ----
  if (LAYER == 3) {
    const float* bs = bias + f * NC;
#pragma unroll
    for (int nf = 0; nf < 4; ++nf) {
      int col = nf * 16 + (lane & 15);
      float bv = bs[col];
#pragma unroll
      for (int mf = 0; mf < MF; ++mf) {
        int rbase = wm * (MF * 16) + mf * 16 + ((lane >> 4) << 2);
#pragma unroll
        for (int i = 0; i < 4; ++i) {
          int pos = m0 + rbase + i;
          if (pos < cntf) {
            int b = rowlist[f * BB + pos];
            Out[(size_t)b * NC + col] = acc[mf][nf][i] + bv;
          }
        }
      }
    }
  } else {
    const float* bs = bias + f * NH;
#pragma unroll
    for (int nf = 0; nf < 4; ++nf) {
      int col = n0 + wn * 64 + nf * 16 + (lane & 15);
      float bv = bs[col];
#pragma unroll
      for (int mf = 0; mf < MF; ++mf) {
        int rbase = wm * (MF * 16) + mf * 16 + ((lane >> 4) << 2);
#pragma unroll
        for (int i = 0; i < 4; ++i) {
          int pos = m0 + rbase + i;
          if (pos < cntf) {
            float v = fmaxf(acc[mf][nf][i] + bv, 0.0f);
            Hout[(size_t)(goff + pos) * NH + col] = f2bf(v);
          }
        }
      }
    }
  }
}

extern "C" void kernel_launch(void* const* d_in, const int* in_sizes, int n_in,
                              void* d_out, int out_size, void* d_ws, size_t ws_size,
                              hipStream_t stream) {
  const float* graph = (const float*)d_in[0];
  const float* state = (const float*)d_in[1];
  const float* nexts = (const float*)d_in[2];
  const float* W1 = (const float*)d_in[3];
  const float* b1 = (const float*)d_in[4];
  const float* W2 = (const float*)d_in[5];
  const float* b2 = (const float*)d_in[6];
  const float* W3 = (const float*)d_in[7];
  const float* b3 = (const float*)d_in[8];
  float* out = (float*)d_out;
  char* ws = (char*)d_ws;

  const size_t ROWCAP = BB + 128;  // +128 rows: partial-tile staging pad
  const size_t OFF_ROW = 256;
  const size_t OFF_W1T = OFF_ROW + (size_t)NFAC * BB * 4;        // 512KB
  const size_t OFF_W2T = OFF_W1T + (size_t)NFAC * NH * KP1 * 2;  // 21MB
  const size_t OFF_W3T = OFF_W2T + (size_t)NFAC * NH * NH * 2;   // 16.8MB
  const size_t OFF_H1  = OFF_W3T + (size_t)NFAC * NC * NH * 2;   // 1MB
  const size_t OFF_XG  = OFF_H1 + ROWCAP * NH * 2;               // 33.8MB

  int* cnt = (int*)ws;
  int* rowlist = (int*)(ws + OFF_ROW);
  unsigned short* w1t = (unsigned short*)(ws + OFF_W1T);
  unsigned short* w2t = (unsigned short*)(ws + OFF_W2T);
  unsigned short* w3t = (unsigned short*)(ws + OFF_W3T);
  unsigned short* h1  = (unsigned short*)(ws + OFF_H1);
  unsigned short* xg  = (unsigned short*)(ws + OFF_XG);
  unsigned short* h2  = xg;  // reuse: xg dead after layer 1

  hipMemsetAsync(cnt, 0, 64, stream);
  hipMemsetAsync(d_out, 0, (size_t)out_size * sizeof(float), stream);

  bucket_kernel<<<BB / 256, 256, 0, stream>>>(graph, cnt, rowlist);
  gather_x<<<BB / 4, 256, 0, stream>>>(graph, state, nexts, cnt, rowlist, xg);
  transpose_all<<<dim3(16, 20, 24), 256, 0, stream>>>(W1, W2, W3, w1t, w2t, w3t);

  mlp_gemm<1><<<dim3(NH / 128, MTILES), 256, 0, stream>>>(
      xg, w1t, b1, h1, nullptr, cnt, rowlist);
  mlp_gemm<2><<<dim3(NH / 128, MTILES), 256, 0, stream>>>(
      h1, w2t, b2, h2, nullptr, cnt, rowlist);
  mlp_gemm<3><<<dim3(1, MTILES), 256, 0, stream>>>(
      h2, w3t, b3, nullptr, out, cnt, rowlist);
}

// Round 5
// 226.575 us; speedup vs baseline: 1.4825x; 1.4825x over previous
//
#include <hip/hip_runtime.h>

#define BB   16384
#define GENC 216
#define OBS  512
#define NH   1024
#define NC   64
#define NFAC 8
#define NIN  1240
#define KP1  1280   // layer-1 K padded to multiple of 64
#define MTILES 136  // worst-case sum of ceil(cnt_f/128): 128 + 8 partials

typedef __attribute__((ext_vector_type(4))) float f32x4;
typedef __attribute__((ext_vector_type(8))) short short8;
typedef __attribute__((ext_vector_type(4))) short short4v;

__device__ __forceinline__ unsigned short f2bf(float f) {
  union { float f; unsigned u; } x; x.f = f;
  unsigned r = x.u + 0x7fffu + ((x.u >> 16) & 1u);
  return (unsigned short)(r >> 16);
}

__device__ __forceinline__ void gl_lds16(const unsigned short* g, unsigned short* l) {
  __builtin_amdgcn_global_load_lds(
      (const __attribute__((address_space(1))) void*)g,
      (__attribute__((address_space(3))) void*)l, 16, 0, 0);
}

// bijective XCD-chunked swizzle (m204): each XCD gets a contiguous wgid range
__device__ __forceinline__ int xcd_chunk(int gid, int nwg) {
  int q = nwg >> 3, r = nwg & 7, x = gid & 7, p = gid >> 3;
  return (x < r ? x * (q + 1) : r * (q + 1) + (x - r) * q) + p;
}

// ---------- bucket: per-row last-active factor, LDS-aggregated atomics ----------
__global__ void bucket_kernel(const float* __restrict__ graph,
                              int* __restrict__ cnt, int* __restrict__ rowlist) {
  __shared__ int lcnt[NFAC];
  __shared__ int lbase[NFAC];
  int tid = threadIdx.x;
  if (tid < NFAC) lcnt[tid] = 0;
  __syncthreads();
  int b = blockIdx.x * 256 + tid;
  const float* g = graph + (size_t)b * GENC;
  float4 g0 = *(const float4*)g;
  float4 g1 = *(const float4*)(g + 4);
  int f = -1;
  if (g0.x == 1.f) f = 0;
  if (g0.y == 1.f) f = 1;
  if (g0.z == 1.f) f = 2;
  if (g0.w == 1.f) f = 3;
  if (g1.x == 1.f) f = 4;
  if (g1.y == 1.f) f = 5;
  if (g1.z == 1.f) f = 6;
  if (g1.w == 1.f) f = 7;
  int li = 0;
  if (f >= 0) li = atomicAdd(&lcnt[f], 1);
  __syncthreads();
  if (tid < NFAC) lbase[tid] = lcnt[tid] ? atomicAdd(&cnt[tid], lcnt[tid]) : 0;
  __syncthreads();
  if (f >= 0) rowlist[f * BB + lbase[f] + li] = b;
}

// -------- gather active rows (global position), concat + f32->bf16, pad to 1280 --------
__global__ void gather_x(const float* __restrict__ graph,
                         const float* __restrict__ state,
                         const float* __restrict__ nexts,
                         const int* __restrict__ cnt,
                         const int* __restrict__ rowlist,
                         unsigned short* __restrict__ xg) {
  int w = threadIdx.x >> 6, lane = threadIdx.x & 63;
  int pos = blockIdx.x * 4 + w;
  int f = -1, loc = 0, acc = 0;
#pragma unroll
  for (int i = 0; i < NFAC; ++i) {
    int c = cnt[i];
    if (f < 0 && pos < acc + c) { f = i; loc = pos - acc; }
    acc += c;
  }
  if (f < 0) return;  // pos >= total active rows
  int b = rowlist[f * BB + loc];
  unsigned short* dst = xg + (size_t)pos * KP1;
#pragma unroll
  for (int it = 0; it < 5; ++it) {
    int c = it * 64 + lane;  // float4 chunk index, 320 total
    float4 v;
    if (c < 54)       v = *(const float4*)(graph + (size_t)b * GENC + c * 4);
    else if (c < 182) v = *(const float4*)(state + (size_t)b * OBS + (c - 54) * 4);
    else if (c < 310) v = *(const float4*)(nexts + (size_t)b * OBS + (c - 182) * 4);
    else              v = make_float4(0.f, 0.f, 0.f, 0.f);
    short4v s;
    s[0] = (short)f2bf(v.x); s[1] = (short)f2bf(v.y);
    s[2] = (short)f2bf(v.z); s[3] = (short)f2bf(v.w);
    *(short4v*)(dst + c * 4) = s;
  }
}

// ---- merged transpose+convert: f32 [F][K][N] -> bf16 [F][N][KPad] for W1,W2,W3 ----
__global__ void transpose_all(const float* __restrict__ W1,
                              const float* __restrict__ W2,
                              const float* __restrict__ W3,
                              unsigned short* __restrict__ w1t,
                              unsigned short* __restrict__ w2t,
                              unsigned short* __restrict__ w3t) {
  __shared__ unsigned short tile[64][65];
  int z = blockIdx.z;
  const float* src; unsigned short* dst; int K, N, KPad;
  if (z < 8)        { src = W1 + (size_t)z * NIN * NH;       dst = w1t + (size_t)z * NH * KP1; K = NIN; N = NH; KPad = KP1; }
  else if (z < 16)  { src = W2 + (size_t)(z - 8) * NH * NH;  dst = w2t + (size_t)(z - 8) * NH * NH; K = NH; N = NH; KPad = NH; }
  else              { src = W3 + (size_t)(z - 16) * NH * NC; dst = w3t + (size_t)(z - 16) * NC * NH; K = NH; N = NC; KPad = NH; }
  int k0 = blockIdx.y * 64, n0 = blockIdx.x * 64;
  if (k0 >= KPad || n0 >= N) return;
  int tr = threadIdx.x >> 6, tc = threadIdx.x & 63;  // tc = n offset
#pragma unroll
  for (int i = 0; i < 16; ++i) {
    int r = i * 4 + tr;  // k offset
    int k = k0 + r;
    float v = (k < K) ? src[(size_t)k * N + n0 + tc] : 0.0f;
    tile[r][tc] = f2bf(v);
  }
  __syncthreads();
  int kp = threadIdx.x & 31, nb = threadIdx.x >> 5;  // 32 k-pairs x 8 n-slots
#pragma unroll
  for (int i = 0; i < 8; ++i) {
    int n = i * 8 + nb;
    union { short2 s2; unsigned u; } v;
    v.s2.x = (short)tile[kp * 2][n];
    v.s2.y = (short)tile[kp * 2 + 1][n];
    *(unsigned*)(dst + (size_t)(n0 + n) * KPad + k0 + kp * 2) = v.u;
  }
}

// ---------------- grouped GEMM, m97 structure, XCD-chunked tile mapping ----------------
template <int LAYER>
__launch_bounds__(256, 2)
__global__ void mlp_gemm(const unsigned short* __restrict__ Abase,
                         const unsigned short* __restrict__ Wt,
                         const float* __restrict__ bias,
                         unsigned short* __restrict__ Hout,
                         float* __restrict__ Out,
                         const int* __restrict__ cnt,
                         const int* __restrict__ rowlist) {
  constexpr int N  = (LAYER == 3) ? NC : NH;
  constexpr int K  = (LAYER == 1) ? KP1 : NH;
  constexpr int BM = 128;
  constexpr int BN = (LAYER == 3) ? 64 : 128;
  constexpr int NB = (LAYER == 3) ? 1 : (NH / 128);  // n-blocks
  constexpr int NKT = K / 64;
  constexpr int MF = (LAYER == 3) ? 2 : 4;
  constexpr int BI = (LAYER == 3) ? 2 : 4;  // B stage issues/wave

  // XCD-chunked 1D grid -> (m-tile, n-block): contiguous m-tiles per XCD,
  // n fastest within a tile so all n-blocks of an A-panel share one L2.
  const int wg = xcd_chunk(blockIdx.x, MTILES * NB);
  const int ty = wg / NB;
  const int n0 = (wg % NB) * BN;

  // map tile id -> (factor, m0, group offset)
  int f = -1, m0 = 0, goff = 0, cntf = 0;
  {
    int acc = 0, off = 0;
#pragma unroll
    for (int i = 0; i < NFAC; ++i) {
      int c = cnt[i];
      int t = (c + BM - 1) >> 7;
      if (f < 0 && ty < acc + t) { f = i; m0 = (ty - acc) * BM; goff = off; cntf = c; }
      acc += t; off += c;
    }
  }
  if (f < 0) return;

  __shared__ unsigned short As[BM * 64];
  __shared__ unsigned short Bs[BN * 64];

  const int tid = threadIdx.x;
  const int wid = tid >> 6, lane = tid & 63;
  const int wm = (LAYER == 3) ? wid : (wid >> 1);
  const int wn = (LAYER == 3) ? 0 : (wid & 1);

  // per-lane pre-swizzled staging sources (linear LDS dest, swizzled source)
  const int rl = lane >> 3;         // row within 8-row stage group
  const int chs = (lane & 7) ^ rl;  // swizzled 16B chunk
  const unsigned short* pA[4];
  const unsigned short* pB[BI];
  {
    const unsigned short* Aorg = Abase + (size_t)(goff + m0) * K;
    const unsigned short* Borg = Wt + (size_t)f * N * K + (size_t)n0 * K;
#pragma unroll
    for (int i = 0; i < 4; ++i)
      pA[i] = Aorg + (size_t)(wid * 32 + i * 8 + rl) * K + chs * 8;
#pragma unroll
    for (int i = 0; i < BI; ++i)
      pB[i] = Borg + (size_t)(wid * (8 * BI) + i * 8 + rl) * K + chs * 8;
  }

  f32x4 acc[MF][4];
#pragma unroll
  for (int a = 0; a < MF; ++a)
#pragma unroll
    for (int b = 0; b < 4; ++b) acc[a][b] = (f32x4){0.f, 0.f, 0.f, 0.f};

  for (int kt = 0; kt < NKT; ++kt) {
#pragma unroll
    for (int i = 0; i < 4; ++i) {
      gl_lds16(pA[i], &As[(wid * 32 + i * 8) * 64]);
      pA[i] += 64;
    }
#pragma unroll
    for (int i = 0; i < BI; ++i) {
      gl_lds16(pB[i], &Bs[(wid * (8 * BI) + i * 8) * 64]);
      pB[i] += 64;
    }
    __syncthreads();
#pragma unroll
    for (int ks = 0; ks < 2; ++ks) {
      const int kc8 = ks * 4 + (lane >> 4);  // logical 8-elem chunk 0..7
      short8 av[MF], bv[4];
#pragma unroll
      for (int mf = 0; mf < MF; ++mf) {
        int row = wm * (MF * 16) + mf * 16 + (lane & 15);
        av[mf] = *(const short8*)(As + row * 64 + ((kc8 ^ (row & 7)) << 3));
      }
#pragma unroll
      for (int nf = 0; nf < 4; ++nf) {
        int col = wn * 64 + nf * 16 + (lane & 15);
        bv[nf] = *(const short8*)(Bs + col * 64 + ((kc8 ^ (col & 7)) << 3));
      }
#pragma unroll
      for (int mf = 0; mf < MF; ++mf)
#pragma unroll
        for (int nf = 0; nf < 4; ++nf)
          acc[mf][nf] = __builtin_amdgcn_mfma_f32_16x16x32_bf16(
              av[mf], bv[nf], acc[mf][nf], 0, 0, 0);
    }
    __syncthreads();
  }

  // ---- epilogue ----
  if (LAYER == 3) {
    const float* bs = bias + f * NC;
#pragma unroll
    for (int nf = 0; nf < 4; ++nf) {
      int col = nf * 16 + (lane & 15);
      float bv = bs[col];
#pragma unroll
      for (int mf = 0; mf < MF; ++mf) {
        int rbase = wm * (MF * 16) + mf * 16 + ((lane >> 4) << 2);
#pragma unroll
        for (int i = 0; i < 4; ++i) {
          int pos = m0 + rbase + i;
          if (pos < cntf) {
            int b = rowlist[f * BB + pos];
            Out[(size_t)b * NC + col] = acc[mf][nf][i] + bv;
          }
        }
      }
    }
  } else {
    const float* bs = bias + f * NH;
#pragma unroll
    for (int nf = 0; nf < 4; ++nf) {
      int col = n0 + wn * 64 + nf * 16 + (lane & 15);
      float bv = bs[col];
#pragma unroll
      for (int mf = 0; mf < MF; ++mf) {
        int rbase = wm * (MF * 16) + mf * 16 + ((lane >> 4) << 2);
#pragma unroll
        for (int i = 0; i < 4; ++i) {
          int pos = m0 + rbase + i;
          if (pos < cntf) {
            float v = fmaxf(acc[mf][nf][i] + bv, 0.0f);
            Hout[(size_t)(goff + pos) * NH + col] = f2bf(v);
          }
        }
      }
    }
  }
}

extern "C" void kernel_launch(void* const* d_in, const int* in_sizes, int n_in,
                              void* d_out, int out_size, void* d_ws, size_t ws_size,
                              hipStream_t stream) {
  const float* graph = (const float*)d_in[0];
  const float* state = (const float*)d_in[1];
  const float* nexts = (const float*)d_in[2];
  const float* W1 = (const float*)d_in[3];
  const float* b1 = (const float*)d_in[4];
  const float* W2 = (const float*)d_in[5];
  const float* b2 = (const float*)d_in[6];
  const float* W3 = (const float*)d_in[7];
  const float* b3 = (const float*)d_in[8];
  float* out = (float*)d_out;
  char* ws = (char*)d_ws;

  const size_t ROWCAP = BB + 128;  // +128 rows: partial-tile staging pad
  const size_t OFF_ROW = 256;
  const size_t OFF_W1T = OFF_ROW + (size_t)NFAC * BB * 4;        // 512KB
  const size_t OFF_W2T = OFF_W1T + (size_t)NFAC * NH * KP1 * 2;  // 21MB
  const size_t OFF_W3T = OFF_W2T + (size_t)NFAC * NH * NH * 2;   // 16.8MB
  const size_t OFF_H1  = OFF_W3T + (size_t)NFAC * NC * NH * 2;   // 1MB
  const size_t OFF_XG  = OFF_H1 + ROWCAP * NH * 2;               // 33.8MB

  int* cnt = (int*)ws;
  int* rowlist = (int*)(ws + OFF_ROW);
  unsigned short* w1t = (unsigned short*)(ws + OFF_W1T);
  unsigned short* w2t = (unsigned short*)(ws + OFF_W2T);
  unsigned short* w3t = (unsigned short*)(ws + OFF_W3T);
  unsigned short* h1  = (unsigned short*)(ws + OFF_H1);
  unsigned short* xg  = (unsigned short*)(ws + OFF_XG);
  unsigned short* h2  = xg;  // reuse: xg dead after layer 1

  hipMemsetAsync(cnt, 0, 64, stream);
  hipMemsetAsync(d_out, 0, (size_t)out_size * sizeof(float), stream);

  bucket_kernel<<<BB / 256, 256, 0, stream>>>(graph, cnt, rowlist);
  gather_x<<<BB / 4, 256, 0, stream>>>(graph, state, nexts, cnt, rowlist, xg);
  transpose_all<<<dim3(16, 20, 24), 256, 0, stream>>>(W1, W2, W3, w1t, w2t, w3t);

  mlp_gemm<1><<<MTILES * (NH / 128), 256, 0, stream>>>(
      xg, w1t, b1, h1, nullptr, cnt, rowlist);
  mlp_gemm<2><<<MTILES * (NH / 128), 256, 0, stream>>>(
      h1, w2t, b2, h2, nullptr, cnt, rowlist);
  mlp_gemm<3><<<MTILES, 256, 0, stream>>>(
      h2, w3t, b3, nullptr, out, cnt, rowlist);
}